// Round 1
// baseline (1434.292 us; speedup 1.0000x reference)
//
#include <hip/hip_runtime.h>

#define B_N 8192
#define D_N 512
#define K_N 64
#define H_N 256
#define SC  4608   // K*K + D
#define R_N 16     // rows per block
#define NT  256    // threads per block

struct Params {
  const float* x;
  const float* U[3];
  const float* V[3];
  const float* W1[3];
  const float* b1[3];
  const float* W2[3];
  const float* b2[3];
  const float* Wout;
  const float* bout;
  float* out;
};

__global__ __launch_bounds__(NT, 2) void apg_fused(Params p) {
  __shared__ float xs[R_N][D_N];    // 32 KB: current layer input
  __shared__ float h1s[R_N][H_N];   // 16 KB
  __shared__ float hs[R_N][K_N];    //  4 KB
  __shared__ float tmps[R_N][K_N];  //  4 KB

  const int tid = threadIdx.x;
  const int row0 = blockIdx.x * R_N;

  // ---- load x tile (coalesced float4) ----
  {
    const float4* __restrict__ xg = (const float4*)(p.x + (size_t)row0 * D_N);
    float4* xl = (float4*)&xs[0][0];
#pragma unroll
    for (int i = 0; i < (R_N * D_N / 4) / NT; ++i)
      xl[tid + i * NT] = xg[tid + i * NT];
  }
  __syncthreads();

  for (int l = 0; l < 3; ++l) {
    const float* __restrict__ U  = p.U[l];
    const float* __restrict__ V  = p.V[l];
    const float* __restrict__ W1 = p.W1[l];
    const float* __restrict__ b1 = p.b1[l];
    const float* __restrict__ W2 = p.W2[l];
    const float* __restrict__ b2 = p.b2[l];

    // ---- h1 = relu(x @ W1 + b1); thread owns column c = tid, all 16 rows ----
    {
      float acc[R_N];
      const float bb = b1[tid];
#pragma unroll
      for (int r = 0; r < R_N; ++r) acc[r] = bb;
      for (int t = 0; t < D_N; t += 4) {
        const float w0 = W1[(t + 0) * H_N + tid];
        const float w1 = W1[(t + 1) * H_N + tid];
        const float w2 = W1[(t + 2) * H_N + tid];
        const float w3 = W1[(t + 3) * H_N + tid];
#pragma unroll
        for (int r = 0; r < R_N; ++r) {
          const float4 xq = *(const float4*)&xs[r][t];  // LDS broadcast
          acc[r] = fmaf(xq.x, w0, acc[r]);
          acc[r] = fmaf(xq.y, w1, acc[r]);
          acc[r] = fmaf(xq.z, w2, acc[r]);
          acc[r] = fmaf(xq.w, w3, acc[r]);
        }
      }
#pragma unroll
      for (int r = 0; r < R_N; ++r) h1s[r][tid] = fmaxf(acc[r], 0.f);
    }

    // ---- h = x @ U; thread owns (4 rows, col c) ----
    {
      const int c = tid & (K_N - 1);
      const int rb = (tid >> 6) * 4;   // wave-uniform
      float acc[4] = {0.f, 0.f, 0.f, 0.f};
      for (int t = 0; t < D_N; t += 4) {
        const float w0 = U[(t + 0) * K_N + c];
        const float w1 = U[(t + 1) * K_N + c];
        const float w2 = U[(t + 2) * K_N + c];
        const float w3 = U[(t + 3) * K_N + c];
#pragma unroll
        for (int rr = 0; rr < 4; ++rr) {
          const float4 xq = *(const float4*)&xs[rb + rr][t];
          acc[rr] = fmaf(xq.x, w0, acc[rr]);
          acc[rr] = fmaf(xq.y, w1, acc[rr]);
          acc[rr] = fmaf(xq.z, w2, acc[rr]);
          acc[rr] = fmaf(xq.w, w3, acc[rr]);
        }
      }
#pragma unroll
      for (int rr = 0; rr < 4; ++rr) hs[rb + rr][c] = acc[rr];
    }
    __syncthreads();

    // ---- tmp[r][j] = sum_k h[r,k] * s[r, 512+64k+j]
    //      = sum_k h[r,k]*b2[512+64k+j] + sum_t h1[r,t] * (sum_k h[r,k]*W2[t,512+64k+j])
    {
      const int j = tid & 63;
      const int rb = (tid >> 6) * 4;   // wave-uniform
      float acc[4] = {0.f, 0.f, 0.f, 0.f};
      // b2 contribution of s
      for (int k = 0; k < K_N; ++k) {
        const float bc = b2[D_N + (k << 6) + j];
#pragma unroll
        for (int rr = 0; rr < 4; ++rr) acc[rr] = fmaf(hs[rb + rr][k], bc, acc[rr]);
      }
      // main bilinear term, k in register chunks of 8
      for (int k0 = 0; k0 < K_N; k0 += 8) {
        float hk[4][8];
#pragma unroll
        for (int rr = 0; rr < 4; ++rr)
#pragma unroll
          for (int kk = 0; kk < 8; ++kk) hk[rr][kk] = hs[rb + rr][k0 + kk];
        for (int t = 0; t < H_N; ++t) {
          const float* __restrict__ wrow = W2 + (size_t)t * SC + D_N + (k0 << 6) + j;
          float sp[4] = {0.f, 0.f, 0.f, 0.f};
#pragma unroll
          for (int kk = 0; kk < 8; ++kk) {
            const float w = wrow[kk << 6];   // coalesced across j lanes
#pragma unroll
            for (int rr = 0; rr < 4; ++rr) sp[rr] = fmaf(hk[rr][kk], w, sp[rr]);
          }
          const float h10 = h1s[rb + 0][t], h11 = h1s[rb + 1][t];
          const float h12 = h1s[rb + 2][t], h13 = h1s[rb + 3][t];
          acc[0] = fmaf(h10, sp[0], acc[0]);
          acc[1] = fmaf(h11, sp[1], acc[1]);
          acc[2] = fmaf(h12, sp[2], acc[2]);
          acc[3] = fmaf(h13, sp[3], acc[3]);
        }
      }
#pragma unroll
      for (int rr = 0; rr < 4; ++rr) tmps[rb + rr][j] = acc[rr];
    }
    __syncthreads();

    // ---- xnew = relu(tmp @ V + h1 @ W2[:, :512] + b2[:512]), overwrite xs ----
    {
      const int c0 = tid & 127;
      const int rb = (tid >> 7) * 8;   // wave-uniform
      float acc[8][4];
#pragma unroll
      for (int cc = 0; cc < 4; ++cc) {
        const float bb = b2[c0 + 128 * cc];
#pragma unroll
        for (int rr = 0; rr < 8; ++rr) acc[rr][cc] = bb;
      }
      for (int t = 0; t < H_N; ++t) {
        float w[4];
#pragma unroll
        for (int cc = 0; cc < 4; ++cc) w[cc] = W2[(size_t)t * SC + c0 + 128 * cc];
        float h1v[8];
#pragma unroll
        for (int rr = 0; rr < 8; ++rr) h1v[rr] = h1s[rb + rr][t];
#pragma unroll
        for (int rr = 0; rr < 8; ++rr)
#pragma unroll
          for (int cc = 0; cc < 4; ++cc) acc[rr][cc] = fmaf(h1v[rr], w[cc], acc[rr][cc]);
      }
      for (int k = 0; k < K_N; ++k) {
        float v[4];
#pragma unroll
        for (int cc = 0; cc < 4; ++cc) v[cc] = V[(size_t)k * D_N + c0 + 128 * cc];
        float tv[8];
#pragma unroll
        for (int rr = 0; rr < 8; ++rr) tv[rr] = tmps[rb + rr][k];
#pragma unroll
        for (int rr = 0; rr < 8; ++rr)
#pragma unroll
          for (int cc = 0; cc < 4; ++cc) acc[rr][cc] = fmaf(tv[rr], v[cc], acc[rr][cc]);
      }
#pragma unroll
      for (int rr = 0; rr < 8; ++rr)
#pragma unroll
        for (int cc = 0; cc < 4; ++cc)
          xs[rb + rr][c0 + 128 * cc] = fmaxf(acc[rr][cc], 0.f);
    }
    __syncthreads();
  }

  // ---- out = x @ Wout + bout ----
  {
    const int r = tid >> 4;
    const int cl = tid & 15;
    float acc = 0.f;
    for (int c = cl; c < D_N; c += 16)
      acc = fmaf(xs[r][c], p.Wout[c], acc);
#pragma unroll
    for (int s = 1; s < 16; s <<= 1) acc += __shfl_xor(acc, s, 64);
    if (cl == 0) p.out[row0 + r] = acc + p.bout[0];
  }
}

extern "C" void kernel_launch(void* const* d_in, const int* in_sizes, int n_in,
                              void* d_out, int out_size, void* d_ws, size_t ws_size,
                              hipStream_t stream) {
  (void)in_sizes; (void)n_in; (void)d_ws; (void)ws_size; (void)out_size;
  Params p;
  p.x = (const float*)d_in[0];
  for (int l = 0; l < 3; ++l) {
    const int base = 1 + l * 6;
    p.U[l]  = (const float*)d_in[base + 0];
    p.V[l]  = (const float*)d_in[base + 1];
    p.W1[l] = (const float*)d_in[base + 2];
    p.b1[l] = (const float*)d_in[base + 3];
    p.W2[l] = (const float*)d_in[base + 4];
    p.b2[l] = (const float*)d_in[base + 5];
  }
  p.Wout = (const float*)d_in[19];
  p.bout = (const float*)d_in[20];
  p.out  = (float*)d_out;
  hipLaunchKernelGGL(apg_fused, dim3(B_N / R_N), dim3(NT), 0, stream, p);
}

// Round 2
// 499.437 us; speedup vs baseline: 2.8718x; 2.8718x over previous
//
#include <hip/hip_runtime.h>

#define B_N 8192
#define D_N 512
#define K_N 64
#define H_N 256
#define SC  4608   // K*K + D
#define R_T 16     // rows per tile/block
#define NT  256

typedef __attribute__((ext_vector_type(8))) short short8;
typedef __attribute__((ext_vector_type(4))) short short4v;
typedef __attribute__((ext_vector_type(4))) float f32x4;

__device__ __forceinline__ unsigned short f2bf(float f) {
  unsigned int u = __builtin_bit_cast(unsigned int, f);
  u += 0x7fff + ((u >> 16) & 1);      // RNE
  return (unsigned short)(u >> 16);
}
__device__ __forceinline__ float bf2f(unsigned short h) {
  unsigned int u = ((unsigned int)h) << 16;
  return __builtin_bit_cast(float, u);
}

// ---- workspace layout (bf16 elements), per layer ----
// W1T [256][512]  @ 0        (Wt[n][k] = W[k][n])
// UT  [ 64][512]  @ 131072
// W2ST[4096][256] @ 163840   (W2ST[n][t] = W2[t][512+n])
// W2bT[ 512][256] @ 1212416  (W2bT[n][t] = W2[t][n])
// VT  [ 512][ 64] @ 1343488
#define L_ELEMS 1376256

struct PrepParams {
  const float* W1[3]; const float* U[3]; const float* W2[3]; const float* V[3];
  short* ws;
};

__global__ __launch_bounds__(NT) void prep_weights(PrepParams p) {
  const int y = blockIdx.y;           // 0..14
  const int l = y / 5, m = y - 5 * l;
  short* wsl = p.ws + (size_t)l * L_ELEMS;
  const float* in; short* out; int K, N, istride, ioff, kshift;
  switch (m) {
    case 0: in = p.W1[l]; out = wsl;           K = 512; N = 256;  istride = 256;  ioff = 0;   kshift = 9; break;
    case 1: in = p.U[l];  out = wsl + 131072;  K = 512; N = 64;   istride = 64;   ioff = 0;   kshift = 9; break;
    case 2: in = p.W2[l]; out = wsl + 163840;  K = 256; N = 4096; istride = 4608; ioff = 512; kshift = 8; break;
    case 3: in = p.W2[l]; out = wsl + 1212416; K = 256; N = 512;  istride = 4608; ioff = 0;   kshift = 8; break;
    default:in = p.V[l];  out = wsl + 1343488; K = 64;  N = 512;  istride = 512;  ioff = 0;   kshift = 6; break;
  }
  const long e = (long)blockIdx.x * NT + threadIdx.x;
  if (e >= (long)K * N) return;
  const int k = (int)(e & (K - 1));
  const int n = (int)(e >> kshift);
  out[e] = (short)f2bf(in[(size_t)k * istride + ioff + n]);
}

struct Params {
  const float* x;
  const float* b1[3];
  const float* b2[3];
  const float* Wout;
  const float* bout;
  const short* ws;
  float* out;
};

#define XP 520   // xs pitch  (1040 B/row: 16B aligned, rows 2-way bank alias -> free)
#define HP 264   // h1s pitch (528 B/row)
#define TP 72    // tmps pitch (144 B/row)

__global__ __launch_bounds__(NT, 3) void apg_mfma(Params p) {
  __shared__ short xs[R_T][XP];     // 16.6 KB  current layer input, bf16
  __shared__ short h1s[R_T][HP];    //  8.4 KB
  __shared__ short tmps[R_T][TP];   //  2.3 KB
  __shared__ float hs[R_T][68];     //  4.3 KB  h = x@U, f32
  __shared__ float b2s[4096];       // 16.0 KB  b2[512:] for einsum bias

  const int tid = threadIdx.x;
  const int row0 = blockIdx.x * R_T;
  const int w   = tid >> 6;          // wave 0..3
  const int l15 = tid & 15;          // lane & 15
  const int g   = (tid & 63) >> 4;   // lane >> 4 (0..3), wave-uniform groups
  const int koff = g * 8;

  // ---- load x tile -> bf16 LDS ----
  {
    const float4* xg = (const float4*)(p.x + (size_t)row0 * D_N);
    for (int i = tid; i < R_T * D_N / 4; i += NT) {
      float4 v = xg[i];
      const int r = i >> 7;
      const int c = (i & 127) << 2;
      short4v s4 = { (short)f2bf(v.x), (short)f2bf(v.y), (short)f2bf(v.z), (short)f2bf(v.w) };
      *(short4v*)&xs[r][c] = s4;
    }
  }
  __syncthreads();

  for (int l = 0; l < 3; ++l) {
    const short* wsl  = p.ws + (size_t)l * L_ELEMS;
    const short* W1T  = wsl;
    const short* UT   = wsl + 131072;
    const short* W2ST = wsl + 163840;
    const short* W2bT = wsl + 1212416;
    const short* VT   = wsl + 1343488;
    const float* b1 = p.b1[l];
    const float* b2 = p.b2[l];

    // ---- stage A: h1 = relu(x @ W1 + b1); wave w -> n in [64w, 64w+64) ----
    for (int nf = 0; nf < 4; ++nf) {
      const int n0 = (w << 6) + (nf << 4);
      const short* pb = W1T + ((size_t)(n0 + l15) << 9) + koff;
      f32x4 acc = {0.f, 0.f, 0.f, 0.f};
#pragma unroll
      for (int kk = 0; kk < 16; ++kk) {
        short8 a = *(const short8*)&xs[l15][kk * 32 + koff];
        short8 b = *(const short8*)(pb + kk * 32);
        acc = __builtin_amdgcn_mfma_f32_16x16x32_bf16(a, b, acc, 0, 0, 0);
      }
      const float bb = b1[n0 + l15];
#pragma unroll
      for (int i = 0; i < 4; ++i)
        h1s[g * 4 + i][n0 + l15] = (short)f2bf(fmaxf(acc[i] + bb, 0.f));
    }

    // ---- stage B: h = x @ U (f32, no relu); wave w -> n-frag 16w ----
    {
      const int n0 = w << 4;
      const short* pb = UT + ((size_t)(n0 + l15) << 9) + koff;
      f32x4 acc = {0.f, 0.f, 0.f, 0.f};
#pragma unroll
      for (int kk = 0; kk < 16; ++kk) {
        short8 a = *(const short8*)&xs[l15][kk * 32 + koff];
        short8 b = *(const short8*)(pb + kk * 32);
        acc = __builtin_amdgcn_mfma_f32_16x16x32_bf16(a, b, acc, 0, 0, 0);
      }
#pragma unroll
      for (int i = 0; i < 4; ++i) hs[g * 4 + i][n0 + l15] = acc[i];
    }

    // ---- stage b2s: einsum-bias columns into LDS ----
    for (int i = tid; i < K_N * K_N; i += NT) b2s[i] = b2[D_N + i];
    __syncthreads();

    // ---- stage C: tmp[r][j] = sum_k h[r,k] * (h1@W2S + b2S)[r, 64k+j] ----
    {
      const int j0 = w << 4;
      short8 aH[8];
#pragma unroll
      for (int kk = 0; kk < 8; ++kk) aH[kk] = *(const short8*)&h1s[l15][kk * 32 + koff];
      const short* pB = W2ST + ((size_t)(j0 + l15) << 8) + koff;
      float tacc[4] = {0.f, 0.f, 0.f, 0.f};
#pragma unroll 2
      for (int k = 0; k < K_N; ++k) {
        const short* pk = pB + ((size_t)k << 14);     // + k*64*256
        f32x4 s = {0.f, 0.f, 0.f, 0.f};
#pragma unroll
        for (int kk = 0; kk < 8; ++kk) {
          short8 b = *(const short8*)(pk + kk * 32);
          s = __builtin_amdgcn_mfma_f32_16x16x32_bf16(aH[kk], b, s, 0, 0, 0);
        }
        const float b2v = b2s[(k << 6) + j0 + l15];
#pragma unroll
        for (int i = 0; i < 4; ++i)
          tacc[i] += hs[g * 4 + i][k] * (s[i] + b2v);
      }
#pragma unroll
      for (int i = 0; i < 4; ++i) tmps[g * 4 + i][j0 + l15] = (short)f2bf(tacc[i]);
    }
    __syncthreads();

    // ---- stage D: xnew = relu(tmp@V + h1@W2[:, :512] + b2[:512]) -> xs ----
    for (int nb = 0; nb < 8; ++nb) {
      const int n0 = ((nb << 2) + w) << 4;   // waves interleave over 32 n-frags
      f32x4 acc = {0.f, 0.f, 0.f, 0.f};
      const short* pv = VT + ((size_t)(n0 + l15) << 6) + koff;
#pragma unroll
      for (int kk = 0; kk < 2; ++kk) {
        short8 a = *(const short8*)&tmps[l15][kk * 32 + koff];
        short8 b = *(const short8*)(pv + kk * 32);
        acc = __builtin_amdgcn_mfma_f32_16x16x32_bf16(a, b, acc, 0, 0, 0);
      }
      const short* pw = W2bT + ((size_t)(n0 + l15) << 8) + koff;
#pragma unroll
      for (int kk = 0; kk < 8; ++kk) {
        short8 a = *(const short8*)&h1s[l15][kk * 32 + koff];
        short8 b = *(const short8*)(pw + kk * 32);
        acc = __builtin_amdgcn_mfma_f32_16x16x32_bf16(a, b, acc, 0, 0, 0);
      }
      const float bb = b2[n0 + l15];
#pragma unroll
      for (int i = 0; i < 4; ++i)
        xs[g * 4 + i][n0 + l15] = (short)f2bf(fmaxf(acc[i] + bb, 0.f));
    }
    __syncthreads();
  }

  // ---- out = x @ Wout + bout ----
  {
    const int r  = tid >> 4;
    const int cl = tid & 15;
    float acc = 0.f;
    for (int c = cl; c < D_N; c += 16)
      acc = fmaf(bf2f((unsigned short)xs[r][c]), p.Wout[c], acc);
#pragma unroll
    for (int s = 1; s < 16; s <<= 1) acc += __shfl_xor(acc, s, 64);
    if (cl == 0) p.out[row0 + r] = acc + p.bout[0];
  }
}

extern "C" void kernel_launch(void* const* d_in, const int* in_sizes, int n_in,
                              void* d_out, int out_size, void* d_ws, size_t ws_size,
                              hipStream_t stream) {
  (void)in_sizes; (void)n_in; (void)ws_size; (void)out_size;
  PrepParams pp;
  Params p;
  p.x = (const float*)d_in[0];
  for (int l = 0; l < 3; ++l) {
    const int base = 1 + l * 6;
    pp.U[l]  = (const float*)d_in[base + 0];
    pp.V[l]  = (const float*)d_in[base + 1];
    pp.W1[l] = (const float*)d_in[base + 2];
    p.b1[l]  = (const float*)d_in[base + 3];
    pp.W2[l] = (const float*)d_in[base + 4];
    p.b2[l]  = (const float*)d_in[base + 5];
  }
  p.Wout = (const float*)d_in[19];
  p.bout = (const float*)d_in[20];
  p.ws   = (const short*)d_ws;
  p.out  = (float*)d_out;
  pp.ws  = (short*)d_ws;

  hipLaunchKernelGGL(prep_weights, dim3(4096, 15), dim3(NT), 0, stream, pp);
  hipLaunchKernelGGL(apg_mfma, dim3(B_N / R_T), dim3(NT), 0, stream, p);
}

// Round 3
// 487.249 us; speedup vs baseline: 2.9437x; 1.0250x over previous
//
#include <hip/hip_runtime.h>

#define B_N 8192
#define D_N 512
#define K_N 64
#define H_N 256
#define SC  4608   // K*K + D
#define R_T 16     // rows per tile/block
#define NT  256

typedef __attribute__((ext_vector_type(8))) short short8;
typedef __attribute__((ext_vector_type(4))) short short4v;
typedef __attribute__((ext_vector_type(4))) float f32x4;

__device__ __forceinline__ unsigned short f2bf(float f) {
  unsigned int u = __builtin_bit_cast(unsigned int, f);
  u += 0x7fff + ((u >> 16) & 1);      // RNE
  return (unsigned short)(u >> 16);
}
__device__ __forceinline__ float bf2f(unsigned short h) {
  unsigned int u = ((unsigned int)h) << 16;
  return __builtin_bit_cast(float, u);
}

// ---- workspace layout (bf16 elements), per layer ----
// W1T [256][512]  @ 0        (Wt[n][k] = W[k][n])
// UT  [ 64][512]  @ 131072
// W2ST[4096][256] @ 163840   (W2ST[n][t] = W2[t][512+n])
// W2bT[ 512][256] @ 1212416  (W2bT[n][t] = W2[t][n])
// VT  [ 512][ 64] @ 1343488
#define L_ELEMS 1376256

struct PrepParams {
  const float* W1[3]; const float* U[3]; const float* W2[3]; const float* V[3];
  short* ws;
};

__global__ __launch_bounds__(NT) void prep_weights(PrepParams p) {
  const int y = blockIdx.y;           // 0..14
  const int l = y / 5, m = y - 5 * l;
  short* wsl = p.ws + (size_t)l * L_ELEMS;
  const float* in; short* out; int K, N, istride, ioff, kshift;
  switch (m) {
    case 0: in = p.W1[l]; out = wsl;           K = 512; N = 256;  istride = 256;  ioff = 0;   kshift = 9; break;
    case 1: in = p.U[l];  out = wsl + 131072;  K = 512; N = 64;   istride = 64;   ioff = 0;   kshift = 9; break;
    case 2: in = p.W2[l]; out = wsl + 163840;  K = 256; N = 4096; istride = 4608; ioff = 512; kshift = 8; break;
    case 3: in = p.W2[l]; out = wsl + 1212416; K = 256; N = 512;  istride = 4608; ioff = 0;   kshift = 8; break;
    default:in = p.V[l];  out = wsl + 1343488; K = 64;  N = 512;  istride = 512;  ioff = 0;   kshift = 6; break;
  }
  const long total = (long)K * N;
  for (long e = (long)blockIdx.x * NT + threadIdx.x; e < total;
       e += (long)gridDim.x * NT) {
    const int k = (int)(e & (K - 1));
    const int n = (int)(e >> kshift);
    out[e] = (short)f2bf(in[(size_t)k * istride + ioff + n]);
  }
}

struct Params {
  const float* x;
  const float* b1[3];
  const float* b2[3];
  const float* Wout;
  const float* bout;
  const short* ws;
  float* out;
};

#define XP 520   // xs pitch in shorts (16B-aligned rows)
#define HP 264
#define TP 72

__global__ __launch_bounds__(NT, 4) void apg_mfma(Params p) {
  __shared__ short xs[R_T][XP];     // 16.6 KB  current layer input, bf16
  __shared__ short h1s[R_T][HP];    //  8.4 KB
  __shared__ short tmps[R_T][TP];   //  2.3 KB
  __shared__ float hs[R_T][68];     //  4.3 KB  h = x@U, f32

  const int tid = threadIdx.x;
  const int row0 = blockIdx.x * R_T;
  const int w   = tid >> 6;          // wave 0..3
  const int l15 = tid & 15;          // lane & 15
  const int g   = (tid & 63) >> 4;   // 0..3, wave-uniform groups
  const int koff = g * 8;

  // ---- load x tile -> bf16 LDS ----
  {
    const float4* xg = (const float4*)(p.x + (size_t)row0 * D_N);
    for (int i = tid; i < R_T * D_N / 4; i += NT) {
      float4 v = xg[i];
      const int r = i >> 7;
      const int c = (i & 127) << 2;
      short4v s4 = { (short)f2bf(v.x), (short)f2bf(v.y), (short)f2bf(v.z), (short)f2bf(v.w) };
      *(short4v*)&xs[r][c] = s4;
    }
  }
  __syncthreads();

  for (int l = 0; l < 3; ++l) {
    const short* wsl  = p.ws + (size_t)l * L_ELEMS;
    const short* W1T  = wsl;
    const short* UT   = wsl + 131072;
    const short* W2ST = wsl + 163840;
    const short* W2bT = wsl + 1212416;
    const short* VT   = wsl + 1343488;
    const float* b1 = p.b1[l];
    const float* b2 = p.b2[l];

    // ---- stage A: h1 = relu(x @ W1 + b1); wave w -> n in [64w, 64w+64) ----
    for (int nf = 0; nf < 4; ++nf) {
      const int n0 = (w << 6) + (nf << 4);
      const short* pb = W1T + ((size_t)(n0 + l15) << 9) + koff;
      short8 bf[16];
#pragma unroll
      for (int kk = 0; kk < 16; ++kk) bf[kk] = *(const short8*)(pb + kk * 32);
      f32x4 acc = {0.f, 0.f, 0.f, 0.f};
#pragma unroll
      for (int kk = 0; kk < 16; ++kk) {
        short8 a = *(const short8*)&xs[l15][kk * 32 + koff];
        acc = __builtin_amdgcn_mfma_f32_16x16x32_bf16(a, bf[kk], acc, 0, 0, 0);
      }
      const float bb = b1[n0 + l15];
#pragma unroll
      for (int i = 0; i < 4; ++i)
        h1s[g * 4 + i][n0 + l15] = (short)f2bf(fmaxf(acc[i] + bb, 0.f));
    }

    // ---- stage B: h = x @ U (f32, no relu); wave w -> n-frag 16w ----
    {
      const int n0 = w << 4;
      const short* pb = UT + ((size_t)(n0 + l15) << 9) + koff;
      short8 bf[16];
#pragma unroll
      for (int kk = 0; kk < 16; ++kk) bf[kk] = *(const short8*)(pb + kk * 32);
      f32x4 acc = {0.f, 0.f, 0.f, 0.f};
#pragma unroll
      for (int kk = 0; kk < 16; ++kk) {
        short8 a = *(const short8*)&xs[l15][kk * 32 + koff];
        acc = __builtin_amdgcn_mfma_f32_16x16x32_bf16(a, bf[kk], acc, 0, 0, 0);
      }
#pragma unroll
      for (int i = 0; i < 4; ++i) hs[g * 4 + i][n0 + l15] = acc[i];
    }
    __syncthreads();

    // ---- stage C: tmp[r][j] = sum_k h[r,k] * (h1@W2S + b2S)[r, 64k+j] ----
    // register ping-pong: load B frags for k+1 while MFMA-chaining k
    {
      const int j0 = w << 4;
      const short* pB = W2ST + ((size_t)(j0 + l15) << 8) + koff;
      const float* pb2 = b2 + D_N + j0 + l15;
      short8 bA[8], bB[8];
#pragma unroll
      for (int kk = 0; kk < 8; ++kk) bA[kk] = *(const short8*)(pB + kk * 32);
      float b2A = pb2[0], b2B;
      short8 aH[8];
#pragma unroll
      for (int kk = 0; kk < 8; ++kk) aH[kk] = *(const short8*)&h1s[l15][kk * 32 + koff];
      float tacc[4] = {0.f, 0.f, 0.f, 0.f};
#pragma unroll 1
      for (int k = 0; k < K_N; k += 2) {
        {
          const short* pk = pB + ((size_t)(k + 1) << 14);
#pragma unroll
          for (int kk = 0; kk < 8; ++kk) bB[kk] = *(const short8*)(pk + kk * 32);
          b2B = pb2[(k + 1) << 6];
          f32x4 s = {0.f, 0.f, 0.f, 0.f};
#pragma unroll
          for (int kk = 0; kk < 8; ++kk)
            s = __builtin_amdgcn_mfma_f32_16x16x32_bf16(aH[kk], bA[kk], s, 0, 0, 0);
#pragma unroll
          for (int i = 0; i < 4; ++i) tacc[i] += hs[g * 4 + i][k] * (s[i] + b2A);
        }
        {
          const int k2 = (k + 2 < K_N) ? (k + 2) : (K_N - 1);  // tail: redundant load
          const short* pk = pB + ((size_t)k2 << 14);
#pragma unroll
          for (int kk = 0; kk < 8; ++kk) bA[kk] = *(const short8*)(pk + kk * 32);
          b2A = pb2[k2 << 6];
          f32x4 s = {0.f, 0.f, 0.f, 0.f};
#pragma unroll
          for (int kk = 0; kk < 8; ++kk)
            s = __builtin_amdgcn_mfma_f32_16x16x32_bf16(aH[kk], bB[kk], s, 0, 0, 0);
#pragma unroll
          for (int i = 0; i < 4; ++i) tacc[i] += hs[g * 4 + i][k + 1] * (s[i] + b2B);
        }
      }
#pragma unroll
      for (int i = 0; i < 4; ++i) tmps[g * 4 + i][j0 + l15] = (short)f2bf(tacc[i]);
    }
    __syncthreads();

    // ---- stage D: xnew = relu(tmp@V + h1@W2[:, :512] + b2[:512]) -> xs ----
    {
      short8 aT[2], aD[8];
#pragma unroll
      for (int kk = 0; kk < 2; ++kk) aT[kk] = *(const short8*)&tmps[l15][kk * 32 + koff];
#pragma unroll
      for (int kk = 0; kk < 8; ++kk) aD[kk] = *(const short8*)&h1s[l15][kk * 32 + koff];
      for (int nb = 0; nb < 8; ++nb) {
        const int n0 = ((nb << 2) + w) << 4;   // waves interleave over 32 n-frags
        const short* pv = VT + ((size_t)(n0 + l15) << 6) + koff;
        const short* pw = W2bT + ((size_t)(n0 + l15) << 8) + koff;
        short8 bv[2], bw[8];
#pragma unroll
        for (int kk = 0; kk < 2; ++kk) bv[kk] = *(const short8*)(pv + kk * 32);
#pragma unroll
        for (int kk = 0; kk < 8; ++kk) bw[kk] = *(const short8*)(pw + kk * 32);
        f32x4 acc = {0.f, 0.f, 0.f, 0.f};
#pragma unroll
        for (int kk = 0; kk < 2; ++kk)
          acc = __builtin_amdgcn_mfma_f32_16x16x32_bf16(aT[kk], bv[kk], acc, 0, 0, 0);
#pragma unroll
        for (int kk = 0; kk < 8; ++kk)
          acc = __builtin_amdgcn_mfma_f32_16x16x32_bf16(aD[kk], bw[kk], acc, 0, 0, 0);
        const float bb = b2[n0 + l15];
#pragma unroll
        for (int i = 0; i < 4; ++i)
          xs[g * 4 + i][n0 + l15] = (short)f2bf(fmaxf(acc[i] + bb, 0.f));
      }
    }
    __syncthreads();
  }

  // ---- out = x @ Wout + bout ----
  {
    const int r  = tid >> 4;
    const int cl = tid & 15;
    float acc = 0.f;
    for (int c = cl; c < D_N; c += 16)
      acc = fmaf(bf2f((unsigned short)xs[r][c]), p.Wout[c], acc);
#pragma unroll
    for (int s = 1; s < 16; s <<= 1) acc += __shfl_xor(acc, s, 64);
    if (cl == 0) p.out[row0 + r] = acc + p.bout[0];
  }
}

extern "C" void kernel_launch(void* const* d_in, const int* in_sizes, int n_in,
                              void* d_out, int out_size, void* d_ws, size_t ws_size,
                              hipStream_t stream) {
  (void)in_sizes; (void)n_in; (void)ws_size; (void)out_size;
  PrepParams pp;
  Params p;
  p.x = (const float*)d_in[0];
  for (int l = 0; l < 3; ++l) {
    const int base = 1 + l * 6;
    pp.U[l]  = (const float*)d_in[base + 0];
    pp.V[l]  = (const float*)d_in[base + 1];
    pp.W1[l] = (const float*)d_in[base + 2];
    p.b1[l]  = (const float*)d_in[base + 3];
    pp.W2[l] = (const float*)d_in[base + 4];
    p.b2[l]  = (const float*)d_in[base + 5];
  }
  p.Wout = (const float*)d_in[19];
  p.bout = (const float*)d_in[20];
  p.ws   = (const short*)d_ws;
  p.out  = (float*)d_out;
  pp.ws  = (short*)d_ws;

  hipLaunchKernelGGL(prep_weights, dim3(1024, 15), dim3(NT), 0, stream, pp);
  hipLaunchKernelGGL(apg_mfma, dim3(B_N / R_T), dim3(NT), 0, stream, p);
}